// Round 1
// baseline (659.222 us; speedup 1.0000x reference)
//
#include <hip/hip_runtime.h>

#define TPB  256
#define TILE 256   // batches per block-iteration; 256*96B = 24 KB raw
#define NB   2048  // grid-stride; 16384 tiles / 2048 = 8 tiles/block exactly

// LDS layout: each batch = 6 float4 data granules + 1 pad granule = 7 * 16 B = 112 B.
// Granule stride 7 with 8 bank-groups (gcd(7,8)=1) makes both the staging write
// pattern ((f/6)*7 + f%6) and the per-thread read pattern (t*7 + j) uniform across
// bank groups -> conflict-free ds_write_b128 / ds_read_b128.

__device__ __forceinline__ float group_loss(const float4& a, const float4& b, const float4& c) {
    // vectors are (y,z,w) of each float4 (column 0 dropped)
    const float n0 = a.y * a.y + a.z * a.z + a.w * a.w;
    const float n1 = b.y * b.y + b.z * b.z + b.w * b.w;
    const float n2 = c.y * c.y + c.z * c.z + c.w * c.w;
    const float p01 = a.y * b.y + a.z * b.z + a.w * b.w;
    const float p02 = a.y * c.y + a.z * c.z + a.w * c.w;
    const float p12 = b.y * c.y + b.z * c.z + b.w * c.w;
    const float r0 = rsqrtf(n0), r1 = rsqrtf(n1), r2 = rsqrtf(n2);
    const float d01 = p01 * r0 * r1;
    const float d02 = p02 * r0 * r2;
    const float d12 = p12 * r1 * r2;
    // diagonal terms <u_i,u_i> - 1 are ~0 in fp32; contribute ~1e-14 to the mean. Skip.
    return 2.f * (d01 * d01 + d02 * d02 + d12 * d12);
}

__global__ __launch_bounds__(TPB) void reg_loss_k1(
    const float4* __restrict__ in, float* __restrict__ partial, int B)
{
    __shared__ float4 tile[TILE * 7];   // 28 KB padded tile
    __shared__ float  wsum[TPB / 64];
    const int t = threadIdx.x;
    const int nTiles = B / TILE;

    float acc = 0.f;

    int tb = blockIdx.x;
    float4 v[6];
    if (tb < nTiles) {
        const float4* src = in + (size_t)tb * (TILE * 6);
        #pragma unroll
        for (int k = 0; k < 6; ++k) v[k] = src[k * TPB + t];   // fully coalesced
    }

    while (tb < nTiles) {
        const int nxt = tb + gridDim.x;

        // stage current tile into padded LDS
        #pragma unroll
        for (int k = 0; k < 6; ++k) {
            const int f = k * TPB + t;
            const int b = f / 6;           // magic-mul, cheap
            const int s = f - b * 6;
            tile[b * 7 + s] = v[k];
        }
        __syncthreads();

        // issue next tile's global loads EARLY (latency hides under compute)
        float4 w[6];
        if (nxt < nTiles) {
            const float4* src = in + (size_t)nxt * (TILE * 6);
            #pragma unroll
            for (int k = 0; k < 6; ++k) w[k] = src[k * TPB + t];
        }

        // compute from LDS: thread t owns batch t of the tile (conflict-free reads)
        {
            const float4* q = &tile[t * 7];
            const float4 q0 = q[0], q1 = q[1], q2 = q[2];
            const float4 q3 = q[3], q4 = q[4], q5 = q[5];
            acc += group_loss(q0, q1, q2);
            acc += group_loss(q3, q4, q5);
        }
        __syncthreads();

        #pragma unroll
        for (int k = 0; k < 6; ++k) v[k] = w[k];
        tb = nxt;
    }

    // tail (B % TILE != 0) — direct loads, block 0 only (dead at B = 4.19e6)
    if (blockIdx.x == 0) {
        for (int b = nTiles * TILE + t; b < B; b += TPB) {
            const float4* p = in + (size_t)b * 6;
            acc += group_loss(p[0], p[1], p[2]);
            acc += group_loss(p[3], p[4], p[5]);
        }
    }

    // wave (64-lane) reduce, then cross-wave via LDS
    for (int off = 32; off > 0; off >>= 1)
        acc += __shfl_down(acc, off, 64);
    if ((t & 63) == 0) wsum[t >> 6] = acc;
    __syncthreads();
    if (t == 0) {
        float s = 0.f;
        #pragma unroll
        for (int w2 = 0; w2 < TPB / 64; ++w2) s += wsum[w2];
        partial[blockIdx.x] = s;
    }
}

// Reduce partials -> mean (double accumulation, single block).
__global__ __launch_bounds__(TPB) void reg_loss_k2(
    const float* __restrict__ partial, float* __restrict__ out, int n, int B)
{
    __shared__ double wsum[TPB / 64];
    const int t = threadIdx.x;
    double s = 0.0;
    for (int i = t; i < n; i += TPB) s += (double)partial[i];
    for (int off = 32; off > 0; off >>= 1)
        s += __shfl_down(s, off, 64);
    if ((t & 63) == 0) wsum[t >> 6] = s;
    __syncthreads();
    if (t == 0) {
        double tot = 0.0;
        #pragma unroll
        for (int w = 0; w < TPB / 64; ++w) tot += wsum[w];
        out[0] = (float)(tot / (double)B);
    }
}

extern "C" void kernel_launch(void* const* d_in, const int* in_sizes, int n_in,
                              void* d_out, int out_size, void* d_ws, size_t ws_size,
                              hipStream_t stream) {
    const float4* in = (const float4*)d_in[0];
    const int B = in_sizes[0] / 24;            // (B, 6, 4) fp32
    float* partial = (float*)d_ws;

    int nb = NB;
    if ((size_t)nb * sizeof(float) > ws_size)
        nb = (int)(ws_size / sizeof(float));
    if (nb < 1) nb = 1;

    reg_loss_k1<<<nb, TPB, 0, stream>>>(in, partial, B);
    reg_loss_k2<<<1, TPB, 0, stream>>>(partial, (float*)d_out, nb, B);
}

// Round 2
// 560.488 us; speedup vs baseline: 1.1762x; 1.1762x over previous
//
#include <hip/hip_runtime.h>

#define TPB  256
#define TILE 256   // batches per block-iteration; 256*96B = 24 KB raw
#define NB   2048  // 16384 tiles / 2048 blocks = 8 iterations/block exactly

// LDS layout: each batch = 6 float4 data granules + 1 pad granule = 7 * 16 B = 112 B.
// 64-lane b128 access floor is 8 cycles; the 7-granule stride gives a balanced
// bank-quad schedule (8 lanes per start-quad, theoretical 0 extra cycles).

__device__ __forceinline__ float group_loss(const float4& a, const float4& b, const float4& c) {
    // vectors are (y,z,w) of each float4 (column 0 dropped)
    const float n0 = a.y * a.y + a.z * a.z + a.w * a.w;
    const float n1 = b.y * b.y + b.z * b.z + b.w * b.w;
    const float n2 = c.y * c.y + c.z * c.z + c.w * c.w;
    const float p01 = a.y * b.y + a.z * b.z + a.w * b.w;
    const float p02 = a.y * c.y + a.z * c.z + a.w * c.w;
    const float p12 = b.y * c.y + b.z * c.z + b.w * c.w;
    const float r0 = rsqrtf(n0), r1 = rsqrtf(n1), r2 = rsqrtf(n2);
    const float d01 = p01 * r0 * r1;
    const float d02 = p02 * r0 * r2;
    const float d12 = p12 * r1 * r2;
    // diagonal terms <u_i,u_i> - 1 are ~0 in fp32; contribute ~1e-14 to the mean. Skip.
    return 2.f * (d01 * d01 + d02 * d02 + d12 * d12);
}

__global__ __launch_bounds__(TPB, 4) void reg_loss_k1(
    const float4* __restrict__ in, float* __restrict__ partial, int B)
{
    __shared__ float4 tile[TILE * 7];   // 28 KB padded tile -> 5 blocks/CU resident
    __shared__ float  wsum[TPB / 64];
    const int t = threadIdx.x;
    const int nTiles = B / TILE;

    float acc = 0.f;

    for (int tb = blockIdx.x; tb < nTiles; tb += gridDim.x) {
        // fully-coalesced global loads (issued before the barrier; latency
        // overlaps the barrier wait + other resident blocks' compute)
        const float4* src = in + (size_t)tb * (TILE * 6);
        float4 v[6];
        #pragma unroll
        for (int k = 0; k < 6; ++k) v[k] = src[k * TPB + t];

        // protect previous iteration's LDS reads before overwriting
        __syncthreads();

        #pragma unroll
        for (int k = 0; k < 6; ++k) {
            const int f = k * TPB + t;
            const int b = f / 6;           // const-div -> magic mul
            const int s = f - b * 6;
            tile[b * 7 + s] = v[k];
        }
        __syncthreads();

        // compute from LDS: thread t owns batch t of the tile
        const float4* q = &tile[t * 7];
        acc += group_loss(q[0], q[1], q[2]);
        acc += group_loss(q[3], q[4], q[5]);
        // no trailing sync: next iteration's leading sync protects the tile
    }

    // tail (B % TILE != 0) — direct loads, block 0 only (dead at B = 4.19e6)
    if (blockIdx.x == 0) {
        for (int b = nTiles * TILE + t; b < B; b += TPB) {
            const float4* p = in + (size_t)b * 6;
            acc += group_loss(p[0], p[1], p[2]);
            acc += group_loss(p[3], p[4], p[5]);
        }
    }

    // wave (64-lane) reduce, then cross-wave via LDS
    for (int off = 32; off > 0; off >>= 1)
        acc += __shfl_down(acc, off, 64);
    if ((t & 63) == 0) wsum[t >> 6] = acc;
    __syncthreads();
    if (t == 0) {
        float s = 0.f;
        #pragma unroll
        for (int w2 = 0; w2 < TPB / 64; ++w2) s += wsum[w2];
        partial[blockIdx.x] = s;
    }
}

// Reduce partials -> mean (double accumulation, single block).
__global__ __launch_bounds__(TPB) void reg_loss_k2(
    const float* __restrict__ partial, float* __restrict__ out, int n, int B)
{
    __shared__ double wsum[TPB / 64];
    const int t = threadIdx.x;
    double s = 0.0;
    for (int i = t; i < n; i += TPB) s += (double)partial[i];
    for (int off = 32; off > 0; off >>= 1)
        s += __shfl_down(s, off, 64);
    if ((t & 63) == 0) wsum[t >> 6] = s;
    __syncthreads();
    if (t == 0) {
        double tot = 0.0;
        #pragma unroll
        for (int w = 0; w < TPB / 64; ++w) tot += wsum[w];
        out[0] = (float)(tot / (double)B);
    }
}

extern "C" void kernel_launch(void* const* d_in, const int* in_sizes, int n_in,
                              void* d_out, int out_size, void* d_ws, size_t ws_size,
                              hipStream_t stream) {
    const float4* in = (const float4*)d_in[0];
    const int B = in_sizes[0] / 24;            // (B, 6, 4) fp32
    float* partial = (float*)d_ws;

    int nb = NB;
    if ((size_t)nb * sizeof(float) > ws_size)
        nb = (int)(ws_size / sizeof(float));
    if (nb < 1) nb = 1;

    reg_loss_k1<<<nb, TPB, 0, stream>>>(in, partial, B);
    reg_loss_k2<<<1, TPB, 0, stream>>>(partial, (float*)d_out, nb, B);
}

// Round 3
// 486.804 us; speedup vs baseline: 1.3542x; 1.1514x over previous
//
#include <hip/hip_runtime.h>

#define TPB  256
#define TILE 128            // batches per phase; 128*96 B = 12 KB raw
#define PAD7 (TILE * 7)     // 896 granules per buffer (stride-7 padded)
#define NB   2048           // 32768 tiles / 2048 blocks = 16 phases/block exactly

typedef float f32x4 __attribute__((ext_vector_type(4)));

// LDS layout: each batch = 6 float4 data granules + 1 pad granule (112 B).
// Read side: thread t reads granules 7*(t>>1) + 3*(t&1) + {0,1,2}; per b128
// instruction the 64 lanes land 8-per-bank-quad -> conflict-free.
// Write side: granule (f/6)*7 + f%6 for f = k*256+t -> near-uniform quads.

__device__ __forceinline__ float group_loss(f32x4 a, f32x4 b, f32x4 c) {
    // vectors are (y,z,w) of each float4 (column 0 dropped)
    const float n0 = a.y * a.y + a.z * a.z + a.w * a.w;
    const float n1 = b.y * b.y + b.z * b.z + b.w * b.w;
    const float n2 = c.y * c.y + c.z * c.z + c.w * c.w;
    const float p01 = a.y * b.y + a.z * b.z + a.w * b.w;
    const float p02 = a.y * c.y + a.z * c.z + a.w * c.w;
    const float p12 = b.y * c.y + b.z * c.z + b.w * c.w;
    const float r0 = rsqrtf(n0), r1 = rsqrtf(n1), r2 = rsqrtf(n2);
    const float d01 = p01 * r0 * r1;
    const float d02 = p02 * r0 * r2;
    const float d12 = p12 * r1 * r2;
    // diagonal terms <u_i,u_i> - 1 are ~0 in fp32; contribute ~1e-14 to the mean. Skip.
    return 2.f * (d01 * d01 + d02 * d02 + d12 * d12);
}

__global__ __launch_bounds__(TPB, 4) void reg_loss_k1(
    const f32x4* __restrict__ in, float* __restrict__ partial, int B)
{
    __shared__ f32x4 tile[2][PAD7];   // 28 KB -> 5 blocks/CU resident
    __shared__ float wsum[TPB / 64];
    const int t = threadIdx.x;
    const int nTiles = B / TILE;

    float acc = 0.f;

    // compute-side base: thread t owns batch t>>1, group t&1 of the tile
    const int goff = (t >> 1) * 7 + 3 * (t & 1);

    // write-side granule addresses (computed once)
    int wa[3];
    #pragma unroll
    for (int k = 0; k < 3; ++k) {
        const int f = k * TPB + t;
        const int b = f / 6;
        wa[k] = b * 7 + (f - b * 6);
    }

    int tb = blockIdx.x;
    f32x4 va[3], vb[3];
    if (tb < nTiles) {
        const f32x4* s = in + (size_t)tb * (TILE * 6);
        #pragma unroll
        for (int k = 0; k < 3; ++k) va[k] = __builtin_nontemporal_load(s + k * TPB + t);
    }

    while (tb < nTiles) {
        // ---- phase A: stage va -> buf0, prefetch vb, compute buf0 ----
        #pragma unroll
        for (int k = 0; k < 3; ++k) tile[0][wa[k]] = va[k];
        const int tn = tb + gridDim.x;
        if (tn < nTiles) {
            const f32x4* s = in + (size_t)tn * (TILE * 6);
            #pragma unroll
            for (int k = 0; k < 3; ++k) vb[k] = __builtin_nontemporal_load(s + k * TPB + t);
        }
        __syncthreads();
        acc += group_loss(tile[0][goff], tile[0][goff + 1], tile[0][goff + 2]);

        if (tn >= nTiles) break;

        // ---- phase B: stage vb -> buf1, prefetch va, compute buf1 ----
        #pragma unroll
        for (int k = 0; k < 3; ++k) tile[1][wa[k]] = vb[k];
        tb = tn + gridDim.x;
        if (tb < nTiles) {
            const f32x4* s = in + (size_t)tb * (TILE * 6);
            #pragma unroll
            for (int k = 0; k < 3; ++k) va[k] = __builtin_nontemporal_load(s + k * TPB + t);
        }
        __syncthreads();
        acc += group_loss(tile[1][goff], tile[1][goff + 1], tile[1][goff + 2]);
    }

    // tail (B % TILE != 0) — direct loads, block 0 only (dead at B = 4.19e6)
    if (blockIdx.x == 0) {
        for (int b = nTiles * TILE + t; b < B; b += TPB) {
            const f32x4* p = in + (size_t)b * 6;
            acc += group_loss(p[0], p[1], p[2]);
            acc += group_loss(p[3], p[4], p[5]);
        }
    }

    // wave (64-lane) reduce, then cross-wave via LDS
    for (int off = 32; off > 0; off >>= 1)
        acc += __shfl_down(acc, off, 64);
    if ((t & 63) == 0) wsum[t >> 6] = acc;
    __syncthreads();
    if (t == 0) {
        float s = 0.f;
        #pragma unroll
        for (int w2 = 0; w2 < TPB / 64; ++w2) s += wsum[w2];
        partial[blockIdx.x] = s;
    }
}

// Reduce partials -> mean (double accumulation, single block).
__global__ __launch_bounds__(TPB) void reg_loss_k2(
    const float* __restrict__ partial, float* __restrict__ out, int n, int B)
{
    __shared__ double wsum[TPB / 64];
    const int t = threadIdx.x;
    double s = 0.0;
    for (int i = t; i < n; i += TPB) s += (double)partial[i];
    for (int off = 32; off > 0; off >>= 1)
        s += __shfl_down(s, off, 64);
    if ((t & 63) == 0) wsum[t >> 6] = s;
    __syncthreads();
    if (t == 0) {
        double tot = 0.0;
        #pragma unroll
        for (int w = 0; w < TPB / 64; ++w) tot += wsum[w];
        out[0] = (float)(tot / (double)B);
    }
}

extern "C" void kernel_launch(void* const* d_in, const int* in_sizes, int n_in,
                              void* d_out, int out_size, void* d_ws, size_t ws_size,
                              hipStream_t stream) {
    const f32x4* in = (const f32x4*)d_in[0];
    const int B = in_sizes[0] / 24;            // (B, 6, 4) fp32
    float* partial = (float*)d_ws;

    int nb = NB;
    if ((size_t)nb * sizeof(float) > ws_size)
        nb = (int)(ws_size / sizeof(float));
    if (nb < 1) nb = 1;

    reg_loss_k1<<<nb, TPB, 0, stream>>>(in, partial, B);
    reg_loss_k2<<<1, TPB, 0, stream>>>(partial, (float*)d_out, nb, B);
}